// Round 1
// baseline (4057.322 us; speedup 1.0000x reference)
//
#include <hip/hip_runtime.h>
#include <math.h>

// ---------- types ----------
typedef __bf16 bf16;
typedef __bf16 bf16x4 __attribute__((ext_vector_type(4)));
typedef __bf16 bf16x8 __attribute__((ext_vector_type(8)));
typedef float  f32x4  __attribute__((ext_vector_type(4)));

__device__ __forceinline__ f32x4 mfma16(bf16x8 a, bf16x8 b, f32x4 c) {
  return __builtin_amdgcn_mfma_f32_16x16x32_bf16(a, b, c, 0, 0, 0);
}

// ---------- model constants ----------
#define SEQ   1024
#define HID   1024
#define NQKV  1280   // Q_OUT(1024) + K_OUT(128) + V_OUT(128)
#define DFF   4096
#define HIST  256
#define KVSEQ 1280   // HIST + SEQ
#define CTL   512
#define NHEAD 16     // H_KV * GROUPS

// =====================================================================
// L2 normalize (x * rsqrt(sum(x^2))) -> bf16
// =====================================================================
__global__ __launch_bounds__(256) void l2norm_kernel(const float* __restrict__ x,
                                                     bf16* __restrict__ out) {
  const int row = blockIdx.x, tid = threadIdx.x;
  const float* xr = x + row * HID;
  float v[4];
  float s = 0.f;
#pragma unroll
  for (int i = 0; i < 4; ++i) { v[i] = xr[tid + i * 256]; s += v[i] * v[i]; }
#pragma unroll
  for (int off = 1; off < 64; off <<= 1) s += __shfl_xor(s, off);
  __shared__ float ws4[4];
  if ((tid & 63) == 0) ws4[tid >> 6] = s;
  __syncthreads();
  s = ws4[0] + ws4[1] + ws4[2] + ws4[3];
  const float sc = rsqrtf(s);
  bf16* orow = out + row * HID;
#pragma unroll
  for (int i = 0; i < 4; ++i) orow[tid + i * 256] = (bf16)(v[i] * sc);
}

// =====================================================================
// Final norm: hn = x * rsqrt(mean(x^2)+1e-6) * norm_w
// writes hn (bf16, all rows) and x[row<CTL] = hn (fp32)
// =====================================================================
__global__ __launch_bounds__(256) void finalnorm_kernel(float* __restrict__ x,
                                                        const float* __restrict__ nw,
                                                        bf16* __restrict__ hn) {
  const int row = blockIdx.x, tid = threadIdx.x;
  float* xr = x + row * HID;
  float v[4];
  float s = 0.f;
#pragma unroll
  for (int i = 0; i < 4; ++i) { v[i] = xr[tid + i * 256]; s += v[i] * v[i]; }
#pragma unroll
  for (int off = 1; off < 64; off <<= 1) s += __shfl_xor(s, off);
  __shared__ float ws4[4];
  if ((tid & 63) == 0) ws4[tid >> 6] = s;
  __syncthreads();
  s = ws4[0] + ws4[1] + ws4[2] + ws4[3];
  const float sc = rsqrtf(s * (1.0f / HID) + 1e-6f);
  bf16* hr = hn + row * HID;
#pragma unroll
  for (int i = 0; i < 4; ++i) {
    const int c = tid + i * 256;
    const float hv = v[i] * sc * nw[c];
    hr[c] = (bf16)hv;
    if (row < CTL) xr[c] = hv;
  }
}

// =====================================================================
// GEMM: C[n,m] = sum_k A[n,k]*B[m,k] (+ res[n,m]); A bf16, B fp32 (cast
// to bf16 in staging), C fp32. grid = (M/BM, N/BN), 256 thr (4 waves 2x2).
// =====================================================================
template<int BN, int BM>
__global__ __launch_bounds__(256) void gemm_bt(const bf16* __restrict__ A,
                                               const float* __restrict__ B,
                                               float* __restrict__ C,
                                               const float* __restrict__ res,
                                               int N, int M, int K) {
  constexpr int LDT = 40;  // lds row stride (bf16): 80B = 16B-aligned, bank period 8
  __shared__ bf16 As[BN * LDT];
  __shared__ bf16 Bs[BM * LDT];
  const int mb = blockIdx.x, nb = blockIdx.y;
  const int tid = threadIdx.x;
  const int w = tid >> 6, lane = tid & 63, l15 = lane & 15, quad = lane >> 4;
  constexpr int WN = BN / 2, WM = BM / 2;
  constexpr int TI = WN / 16, TJ = WM / 16;
  const int wr = (w >> 1) * WN, wc = (w & 1) * WM;
  f32x4 acc[TI][TJ] = {};
  const int ar = tid >> 2, ac = (tid & 3) * 8;  // A: 4 thr/row, 8 bf16 each
  const int br = tid >> 3, bc = (tid & 7) * 4;  // B: 8 thr/row, 4 f32 each
  const bf16*  Abase = A + (size_t)(nb * BN) * K;
  const float* Bbase = B + (size_t)(mb * BM) * K;

  for (int kk = 0; kk < K; kk += 32) {
#pragma unroll
    for (int i = 0; i < BN / 64; ++i) {
      const int r = ar + i * 64;
      bf16x8 v = *(const bf16x8*)(Abase + (size_t)r * K + kk + ac);
      *(bf16x8*)(&As[r * LDT + ac]) = v;
    }
#pragma unroll
    for (int i = 0; i < BM / 32; ++i) {
      const int r = br + i * 32;
      float4 f = *(const float4*)(Bbase + (size_t)r * K + kk + bc);
      bf16x4 h;
      h.x = (bf16)f.x; h.y = (bf16)f.y; h.z = (bf16)f.z; h.w = (bf16)f.w;
      *(bf16x4*)(&Bs[r * LDT + bc]) = h;
    }
    __syncthreads();
    bf16x8 a[TI], b[TJ];
#pragma unroll
    for (int i = 0; i < TI; ++i)
      a[i] = *(const bf16x8*)(&As[(wr + i * 16 + l15) * LDT + quad * 8]);
#pragma unroll
    for (int j = 0; j < TJ; ++j)
      b[j] = *(const bf16x8*)(&Bs[(wc + j * 16 + l15) * LDT + quad * 8]);
#pragma unroll
    for (int i = 0; i < TI; ++i)
#pragma unroll
      for (int j = 0; j < TJ; ++j)
        acc[i][j] = mfma16(a[i], b[j], acc[i][j]);
    __syncthreads();
  }

#pragma unroll
  for (int i = 0; i < TI; ++i)
#pragma unroll
    for (int j = 0; j < TJ; ++j)
#pragma unroll
      for (int r = 0; r < 4; ++r) {
        const int row = nb * BN + wr + i * 16 + quad * 4 + r;
        const int col = mb * BM + wc + j * 16 + l15;
        const size_t idx = (size_t)row * M + col;
        float v = acc[i][j][r];
        if (res) v += res[idx];
        C[idx] = v;
      }
}

// =====================================================================
// prep: RoPE on q/k, pack q (bf16 [s][16*64]), k_full (bf16 [kv][1280][64]),
// v_full (bf16 [kv][1280][64]); cache rows 0..255 come from k_cache
// ([kv][64][256], transposed) and v_cache ([kv][256][64]).
// =====================================================================
__global__ __launch_bounds__(256) void prep_kernel(const float* __restrict__ qkv,
                                                   const float* __restrict__ kc,
                                                   const float* __restrict__ vc,
                                                   bf16* __restrict__ q,
                                                   bf16* __restrict__ kf,
                                                   bf16* __restrict__ vf) {
  int id = blockIdx.x * 256 + threadIdx.x;
  if (id < SEQ * HID) {                       // ---- q RoPE
    const int s = id >> 10, c = id & 1023;
    const int d = c & 63, j = d & 31;
    const float pos = (float)(HIST + s);
    const float inv = powf(10000.0f, -(float)(2 * j) / 64.0f);
    float sn, cs; sincosf(pos * inv, &sn, &cs);
    const float v0 = qkv[(size_t)s * NQKV + c];
    const float vp = (d < 32) ? qkv[(size_t)s * NQKV + c + 32]
                              : qkv[(size_t)s * NQKV + c - 32];
    const float r = (d < 32) ? (v0 * cs - vp * sn) : (v0 * cs + vp * sn);
    q[(size_t)s * HID + c] = (bf16)r;
    return;
  }
  id -= SEQ * HID;
  if (id < SEQ * 128) {                       // ---- k new RoPE
    const int s = id >> 7, c = id & 127;
    const int kvh = c >> 6, d = c & 63, j = d & 31;
    const float pos = (float)(HIST + s);
    const float inv = powf(10000.0f, -(float)(2 * j) / 64.0f);
    float sn, cs; sincosf(pos * inv, &sn, &cs);
    const float v0 = qkv[(size_t)s * NQKV + 1024 + c];
    const float vp = (d < 32) ? qkv[(size_t)s * NQKV + 1024 + c + 32]
                              : qkv[(size_t)s * NQKV + 1024 + c - 32];
    const float r = (d < 32) ? (v0 * cs - vp * sn) : (v0 * cs + vp * sn);
    kf[(size_t)kvh * KVSEQ * 64 + (size_t)(HIST + s) * 64 + d] = (bf16)r;
    return;
  }
  id -= SEQ * 128;
  if (id < SEQ * 128) {                       // ---- v new
    const int s = id >> 7, c = id & 127;
    const int kvh = c >> 6, d = c & 63;
    vf[(size_t)kvh * KVSEQ * 64 + (size_t)(HIST + s) * 64 + d] =
        (bf16)qkv[(size_t)s * NQKV + 1152 + c];
    return;
  }
  id -= SEQ * 128;
  if (id < 2 * 64 * HIST) {                   // ---- k cache (transpose)
    const int kvh = id >> 14, rem = id & 16383;
    const int d = rem >> 8, t = rem & 255;
    kf[(size_t)kvh * KVSEQ * 64 + (size_t)t * 64 + d] =
        (bf16)kc[(size_t)kvh * 64 * HIST + (size_t)d * HIST + t];
    return;
  }
  id -= 2 * 64 * HIST;
  {                                           // ---- v cache
    const int kvh = id >> 14, rem = id & 16383;
    const int t = rem >> 6, d = rem & 63;
    vf[(size_t)kvh * KVSEQ * 64 + (size_t)t * 64 + d] =
        (bf16)vc[(size_t)kvh * HIST * 64 + (size_t)t * 64 + d];
  }
}

// =====================================================================
// Flash attention. grid (16 q-blocks, 16 heads), 256 thr (4 waves).
// Wave handles 16 q rows. Online softmax, soft causal mask (-128*mask),
// early exit past the causal frontier. Writes o bf16 [s][h*64+d].
// =====================================================================
__global__ __launch_bounds__(256) void attn_kernel(const bf16* __restrict__ q,
                                                   const bf16* __restrict__ kf,
                                                   const bf16* __restrict__ vf,
                                                   const float* __restrict__ mask,
                                                   bf16* __restrict__ o) {
  const int qb = blockIdx.x;       // q block of 64 rows
  const int h  = blockIdx.y;       // head 0..15
  const int kvh = h >> 3;
  const int tid = threadIdx.x;
  const int w = tid >> 6, lane = tid & 63, l15 = lane & 15, quad = lane >> 4;
  const float negm = -128.0f * mask[0];

  __shared__ bf16 Vt[64 * 40];        // V^T tile: [d][kv32], stride 40
  __shared__ bf16 Pl[4][16 * 40];     // per-wave P: [qrow16][kv32], stride 40

  const int qr = qb * 64 + w * 16 + l15;
  const bf16* qbase = q + (size_t)qr * HID + h * 64;
  const bf16x8 aQ0 = *(const bf16x8*)(qbase + quad * 8);
  const bf16x8 aQ1 = *(const bf16x8*)(qbase + 32 + quad * 8);

  f32x4 Oacc[4] = {};
  float m_i[4], l_i[4];
#pragma unroll
  for (int r = 0; r < 4; ++r) { m_i[r] = -INFINITY; l_i[r] = 0.f; }

  const int qrow0 = qb * 64 + w * 16 + quad * 4;
  const int ntiles = qb * 2 + 2;   // kv limit = qb*64+64, tiles of 32
  const bf16* kbase = kf + (size_t)kvh * KVSEQ * 64;
  const bf16* vbase = vf + (size_t)kvh * KVSEQ * 64;
  bf16* pw = &Pl[w][0];

  for (int t = 0; t < ntiles; ++t) {
    __syncthreads();   // protect Vt from previous iteration's readers
    {
      const int vp = tid >> 3, d0 = (tid & 7) * 8;
      bf16x8 vv = *(const bf16x8*)(vbase + (size_t)(t * 32 + vp) * 64 + d0);
#pragma unroll
      for (int jj = 0; jj < 8; ++jj) Vt[(d0 + jj) * 40 + vp] = vv[jj];
    }
    __syncthreads();

    f32x4 S[2];
#pragma unroll
    for (int u = 0; u < 2; ++u) {
      const bf16* kp = kbase + (size_t)(t * 32 + u * 16 + l15) * 64;
      bf16x8 b0 = *(const bf16x8*)(kp + quad * 8);
      bf16x8 b1 = *(const bf16x8*)(kp + 32 + quad * 8);
      f32x4 z = {0.f, 0.f, 0.f, 0.f};
      S[u] = mfma16(aQ0, b0, z);
      S[u] = mfma16(aQ1, b1, S[u]);
    }
    const int kj = t * 32 + l15;
#pragma unroll
    for (int u = 0; u < 2; ++u)
#pragma unroll
      for (int r = 0; r < 4; ++r)
        S[u][r] += ((kj + u * 16) <= (qrow0 + r)) ? 0.f : negm;

    float p0[4], p1[4];
#pragma unroll
    for (int r = 0; r < 4; ++r) {
      float vm = fmaxf(S[0][r], S[1][r]);
#pragma unroll
      for (int off = 1; off < 16; off <<= 1) vm = fmaxf(vm, __shfl_xor(vm, off));
      const float mnew = fmaxf(m_i[r], vm);
      const float alpha = __expf(m_i[r] - mnew);
      p0[r] = __expf(S[0][r] - mnew);
      p1[r] = __expf(S[1][r] - mnew);
      float rs = p0[r] + p1[r];
#pragma unroll
      for (int off = 1; off < 16; off <<= 1) rs += __shfl_xor(rs, off);
      l_i[r] = l_i[r] * alpha + rs;
      m_i[r] = mnew;
#pragma unroll
      for (int j = 0; j < 4; ++j) Oacc[j][r] *= alpha;
    }

    // P (D-layout) -> LDS -> A-layout fragment (wave-private)
#pragma unroll
    for (int r = 0; r < 4; ++r) {
      pw[(quad * 4 + r) * 40 + l15]      = (bf16)p0[r];
      pw[(quad * 4 + r) * 40 + 16 + l15] = (bf16)p1[r];
    }
    const bf16x8 aP = *(const bf16x8*)(pw + l15 * 40 + quad * 8);
#pragma unroll
    for (int j = 0; j < 4; ++j) {
      bf16x8 bV = *(const bf16x8*)(&Vt[(j * 16 + l15) * 40 + quad * 8]);
      Oacc[j] = mfma16(aP, bV, Oacc[j]);
    }
  }

#pragma unroll
  for (int j = 0; j < 4; ++j)
#pragma unroll
    for (int r = 0; r < 4; ++r) {
      const int row = qb * 64 + w * 16 + quad * 4 + r;
      o[(size_t)row * HID + h * 64 + j * 16 + l15] = (bf16)(Oacc[j][r] / l_i[r]);
    }
}

// =====================================================================
// silu(gate)*up -> bf16
// =====================================================================
__global__ __launch_bounds__(256) void silu_kernel(const float* __restrict__ gu,
                                                   bf16* __restrict__ h) {
  const int id = blockIdx.x * 256 + threadIdx.x;  // SEQ*DFF total
  const int s = id >> 12, j = id & 4095;
  const float g = gu[(size_t)s * (2 * DFF) + j];
  const float u = gu[(size_t)s * (2 * DFF) + DFF + j];
  h[id] = (bf16)(g / (1.0f + __expf(-g)) * u);
}

// =====================================================================
// launch
// =====================================================================
extern "C" void kernel_launch(void* const* d_in, const int* in_sizes, int n_in,
                              void* d_out, int out_size, void* d_ws, size_t ws_size,
                              hipStream_t stream) {
  const float* hidden  = (const float*)d_in[0];
  const float* feat    = (const float*)d_in[1];
  const float* qkv_w   = (const float*)d_in[2];
  const float* o_w     = (const float*)d_in[3];
  const float* gu_w    = (const float*)d_in[4];
  const float* down_w  = (const float*)d_in[5];
  const float* norm_w  = (const float*)d_in[6];
  const float* fsq_w   = (const float*)d_in[7];
  const float* k_cache = (const float*)d_in[8];
  const float* v_cache = (const float*)d_in[9];
  const float* mask    = (const float*)d_in[10];
  float* x = (float*)d_out;   // residual stream lives in d_out

  char* p = (char*)d_ws;
  bf16*  xn   = (bf16*)p;  p += (size_t)SEQ * HID * 2;        // 2 MB
  float* qkvb = (float*)p; p += (size_t)SEQ * NQKV * 4;       // 5.24 MB
  bf16*  qb   = (bf16*)p;  p += (size_t)SEQ * HID * 2;        // 2 MB
  bf16*  kfb  = (bf16*)p;  p += (size_t)2 * KVSEQ * 64 * 2;   // 0.33 MB
  bf16*  vfb  = (bf16*)p;  p += (size_t)2 * KVSEQ * 64 * 2;   // 0.33 MB
  bf16*  ob   = (bf16*)p;  p += (size_t)SEQ * HID * 2;        // 2 MB
  float* gub  = (float*)p; p += (size_t)SEQ * 2 * DFF * 4;    // 32 MB
  bf16*  hb   = (bf16*)p;  p += (size_t)SEQ * DFF * 2;        // 8 MB

  hipMemcpyAsync(x, hidden, (size_t)SEQ * HID * 4, hipMemcpyDeviceToDevice, stream);

  for (int l = 0; l < 12; ++l) {
    if (l == 6) {
      finalnorm_kernel<<<SEQ, 256, 0, stream>>>(x, norm_w, xn);
      // fsq: rows [CTL, SEQ) of hn; C = x+CTL rows, res = feat_embed
      gemm_bt<64, 64><<<dim3(HID / 64, (SEQ - CTL) / 64), 256, 0, stream>>>(
          xn + (size_t)CTL * HID, fsq_w, x + (size_t)CTL * HID, feat,
          SEQ - CTL, HID, HID);
    }
    l2norm_kernel<<<SEQ, 256, 0, stream>>>(x, xn);
    gemm_bt<64, 64><<<dim3(NQKV / 64, SEQ / 64), 256, 0, stream>>>(
        xn, qkv_w + (size_t)l * NQKV * HID, qkvb, nullptr, SEQ, NQKV, HID);
    prep_kernel<<<5376, 256, 0, stream>>>(
        qkvb, k_cache + (size_t)l * 2 * 64 * HIST,
        v_cache + (size_t)l * 2 * HIST * 64, qb, kfb, vfb);
    attn_kernel<<<dim3(SEQ / 64, NHEAD), 256, 0, stream>>>(qb, kfb, vfb, mask, ob);
    gemm_bt<64, 64><<<dim3(HID / 64, SEQ / 64), 256, 0, stream>>>(
        ob, o_w + (size_t)l * HID * HID, x, x, SEQ, HID, HID);
    l2norm_kernel<<<SEQ, 256, 0, stream>>>(x, xn);
    gemm_bt<128, 128><<<dim3(2 * DFF / 128, SEQ / 128), 256, 0, stream>>>(
        xn, gu_w + (size_t)l * 2 * DFF * HID, gub, nullptr, SEQ, 2 * DFF, HID);
    silu_kernel<<<SEQ * DFF / 256, 256, 0, stream>>>(gub, hb);
    gemm_bt<64, 64><<<dim3(HID / 64, SEQ / 64), 256, 0, stream>>>(
        hb, down_w + (size_t)l * HID * DFF, x, x, SEQ, HID, DFF);
  }
}

// Round 2
// 2977.067 us; speedup vs baseline: 1.3629x; 1.3629x over previous
//
#include <hip/hip_runtime.h>
#include <math.h>

// ---------- types ----------
typedef __bf16 bf16;
typedef __bf16 bf16x4 __attribute__((ext_vector_type(4)));
typedef __bf16 bf16x8 __attribute__((ext_vector_type(8)));
typedef float  f32x4  __attribute__((ext_vector_type(4)));

__device__ __forceinline__ f32x4 mfma16(bf16x8 a, bf16x8 b, f32x4 c) {
  return __builtin_amdgcn_mfma_f32_16x16x32_bf16(a, b, c, 0, 0, 0);
}

// async global->LDS, 16B per lane; lds ptr must be wave-uniform (HW adds lane*16)
__device__ __forceinline__ void gl_lds16(const bf16* g, bf16* l) {
  __builtin_amdgcn_global_load_lds(
      (const __attribute__((address_space(1))) void*)g,
      (__attribute__((address_space(3))) void*)l, 16, 0, 0);
}

// ---------- model constants ----------
#define SEQ   1024
#define HID   1024
#define NQKV  1280   // Q_OUT(1024) + K_OUT(128) + V_OUT(128)
#define DFF   4096
#define HIST  256
#define KVSEQ 1280   // HIST + SEQ
#define CTL   512
#define NHEAD 16

// =====================================================================
// fp32 -> bf16 weight conversion for one layer's bundle (+fsq at l==6)
// =====================================================================
#define Q4 327680    // NQKV*HID/4
#define O4 262144    // HID*HID/4
#define G4 2097152   // 2*DFF*HID/4
#define D4 1048576   // HID*DFF/4
#define F4 262144    // HID*HID/4
__global__ __launch_bounds__(256) void convert_kernel(
    const float4* __restrict__ qkv, const float4* __restrict__ o,
    const float4* __restrict__ gu, const float4* __restrict__ dn,
    const float4* __restrict__ fsq,
    bf16x4* __restrict__ wq, bf16x4* __restrict__ wo,
    bf16x4* __restrict__ wgu, bf16x4* __restrict__ wdn,
    bf16x4* __restrict__ wfsq) {
  int id = blockIdx.x * 256 + threadIdx.x;
  const float4* s; bf16x4* d; int off;
  if (id < Q4) { s = qkv; d = wq; off = id; }
  else if ((id -= Q4) < O4) { s = o; d = wo; off = id; }
  else if ((id -= O4) < G4) { s = gu; d = wgu; off = id; }
  else if ((id -= G4) < D4) { s = dn; d = wdn; off = id; }
  else if ((id -= D4) < F4) { if (!fsq) return; s = fsq; d = wfsq; off = id; }
  else return;
  const float4 f = s[off];
  bf16x4 h; h.x = (bf16)f.x; h.y = (bf16)f.y; h.z = (bf16)f.z; h.w = (bf16)f.w;
  d[off] = h;
}

// =====================================================================
// L2 normalize (x * rsqrt(sum(x^2))) -> bf16
// =====================================================================
__global__ __launch_bounds__(256) void l2norm_kernel(const float* __restrict__ x,
                                                     bf16* __restrict__ out) {
  const int row = blockIdx.x, tid = threadIdx.x;
  const float* xr = x + row * HID;
  float v[4];
  float s = 0.f;
#pragma unroll
  for (int i = 0; i < 4; ++i) { v[i] = xr[tid + i * 256]; s += v[i] * v[i]; }
#pragma unroll
  for (int off = 1; off < 64; off <<= 1) s += __shfl_xor(s, off);
  __shared__ float ws4[4];
  if ((tid & 63) == 0) ws4[tid >> 6] = s;
  __syncthreads();
  s = ws4[0] + ws4[1] + ws4[2] + ws4[3];
  const float sc = rsqrtf(s);
  bf16* orow = out + row * HID;
#pragma unroll
  for (int i = 0; i < 4; ++i) orow[tid + i * 256] = (bf16)(v[i] * sc);
}

// =====================================================================
// Final norm: hn = x * rsqrt(mean(x^2)+1e-6) * norm_w
// writes hn (bf16, all rows) and x[row<CTL] = hn (fp32)
// =====================================================================
__global__ __launch_bounds__(256) void finalnorm_kernel(float* __restrict__ x,
                                                        const float* __restrict__ nw,
                                                        bf16* __restrict__ hn) {
  const int row = blockIdx.x, tid = threadIdx.x;
  float* xr = x + row * HID;
  float v[4];
  float s = 0.f;
#pragma unroll
  for (int i = 0; i < 4; ++i) { v[i] = xr[tid + i * 256]; s += v[i] * v[i]; }
#pragma unroll
  for (int off = 1; off < 64; off <<= 1) s += __shfl_xor(s, off);
  __shared__ float ws4[4];
  if ((tid & 63) == 0) ws4[tid >> 6] = s;
  __syncthreads();
  s = ws4[0] + ws4[1] + ws4[2] + ws4[3];
  const float sc = rsqrtf(s * (1.0f / HID) + 1e-6f);
  bf16* hr = hn + row * HID;
#pragma unroll
  for (int i = 0; i < 4; ++i) {
    const int c = tid + i * 256;
    const float hv = v[i] * sc * nw[c];
    hr[c] = (bf16)hv;
    if (row < CTL) xr[c] = hv;
  }
}

// =====================================================================
// GEMM (m97 structure): C[n,m] += A[n,k]*B[m,k]; A,B bf16 K-major, C fp32.
// 128x128 tile, BK=32, 4 waves (2x2, 64x64 each), global_load_lds staging,
// unpadded LDS (row stride 32 bf16), split-K via blockIdx.z + atomic f32 add.
// grid = (M/128, N/128, split); ksteps = K/(32*split).
// =====================================================================
__global__ __launch_bounds__(256) void gemm128(const bf16* __restrict__ A,
                                               const bf16* __restrict__ B,
                                               float* __restrict__ C,
                                               int M, int K, int ksteps) {
  __shared__ __align__(16) bf16 As[128 * 32];
  __shared__ __align__(16) bf16 Bs[128 * 32];
  const int mb = blockIdx.x, nb = blockIdx.y;
  const int tid = threadIdx.x, w = tid >> 6, lane = tid & 63;
  const int l15 = lane & 15, quad = lane >> 4;
  const int wr = (w >> 1) * 64, wc = (w & 1) * 64;
  const int k0 = blockIdx.z * ksteps * 32;

  // staging: 512 16B-chunks per matrix; wave w issues chunks [w*64,+64) and [256+w*64,+64)
  const int c0 = w * 64 + lane, c1 = w * 64 + 256 + lane;
  const bf16* gA0 = A + (size_t)(nb * 128 + (c0 >> 2)) * K + k0 + (c0 & 3) * 8;
  const bf16* gA1 = A + (size_t)(nb * 128 + (c1 >> 2)) * K + k0 + (c1 & 3) * 8;
  const bf16* gB0 = B + (size_t)(mb * 128 + (c0 >> 2)) * K + k0 + (c0 & 3) * 8;
  const bf16* gB1 = B + (size_t)(mb * 128 + (c1 >> 2)) * K + k0 + (c1 & 3) * 8;
  bf16* lA0 = As + (w * 64) * 8;        // wave-uniform LDS bases
  bf16* lA1 = As + (w * 64 + 256) * 8;
  bf16* lB0 = Bs + (w * 64) * 8;
  bf16* lB1 = Bs + (w * 64 + 256) * 8;

  f32x4 acc[4][4] = {};
  for (int ks = 0; ks < ksteps; ++ks) {
    gl_lds16(gA0, lA0); gl_lds16(gA1, lA1);
    gl_lds16(gB0, lB0); gl_lds16(gB1, lB1);
    gA0 += 32; gA1 += 32; gB0 += 32; gB1 += 32;
    __syncthreads();
    bf16x8 a[4], b[4];
#pragma unroll
    for (int i = 0; i < 4; ++i)
      a[i] = *(const bf16x8*)(As + (wr + i * 16 + l15) * 32 + quad * 8);
#pragma unroll
    for (int j = 0; j < 4; ++j)
      b[j] = *(const bf16x8*)(Bs + (wc + j * 16 + l15) * 32 + quad * 8);
#pragma unroll
    for (int i = 0; i < 4; ++i)
#pragma unroll
      for (int j = 0; j < 4; ++j)
        acc[i][j] = mfma16(a[i], b[j], acc[i][j]);
    __syncthreads();
  }

#pragma unroll
  for (int i = 0; i < 4; ++i)
#pragma unroll
    for (int j = 0; j < 4; ++j)
#pragma unroll
      for (int r = 0; r < 4; ++r) {
        const int row = nb * 128 + wr + i * 16 + quad * 4 + r;
        const int col = mb * 128 + wc + j * 16 + l15;
        unsafeAtomicAdd(&C[(size_t)row * M + col], acc[i][j][r]);
      }
}

// =====================================================================
// Fused gate/up GEMM + silu: block computes gate cols [mb*64,+64) and the
// matching up cols; B tile rows 0..63 from gu_w[mb*64+r], 64..127 from
// gu_w[DFF+mb*64+r-64]. 4 waves of 32 rows x 128 cols (TI=2, TJ=8).
// Epilogue writes silu(gate)*up as bf16 to H[n][DFF].
// grid = (DFF/64, SEQ/128).
// =====================================================================
__global__ __launch_bounds__(256) void gemm_gu(const bf16* __restrict__ A,
                                               const bf16* __restrict__ Wg,
                                               bf16* __restrict__ H,
                                               int K) {
  __shared__ __align__(16) bf16 As[128 * 32];
  __shared__ __align__(16) bf16 Bs[128 * 32];
  const int mb = blockIdx.x, nb = blockIdx.y;
  const int tid = threadIdx.x, w = tid >> 6, lane = tid & 63;
  const int l15 = lane & 15, quad = lane >> 4;
  const int wr = w * 32;

  const int c0 = w * 64 + lane, c1 = w * 64 + 256 + lane;
  const int rA0 = c0 >> 2, rA1 = c1 >> 2;
  const int gr0 = (rA0 < 64) ? (mb * 64 + rA0) : (DFF + mb * 64 + rA0 - 64);
  const int gr1 = (rA1 < 64) ? (mb * 64 + rA1) : (DFF + mb * 64 + rA1 - 64);
  const bf16* gA0 = A + (size_t)(nb * 128 + rA0) * K + (c0 & 3) * 8;
  const bf16* gA1 = A + (size_t)(nb * 128 + rA1) * K + (c1 & 3) * 8;
  const bf16* gB0 = Wg + (size_t)gr0 * K + (c0 & 3) * 8;
  const bf16* gB1 = Wg + (size_t)gr1 * K + (c1 & 3) * 8;
  bf16* lA0 = As + (w * 64) * 8;
  bf16* lA1 = As + (w * 64 + 256) * 8;
  bf16* lB0 = Bs + (w * 64) * 8;
  bf16* lB1 = Bs + (w * 64 + 256) * 8;

  f32x4 acc[2][8] = {};
  const int ksteps = K / 32;
  for (int ks = 0; ks < ksteps; ++ks) {
    gl_lds16(gA0, lA0); gl_lds16(gA1, lA1);
    gl_lds16(gB0, lB0); gl_lds16(gB1, lB1);
    gA0 += 32; gA1 += 32; gB0 += 32; gB1 += 32;
    __syncthreads();
    bf16x8 a[2], b[8];
#pragma unroll
    for (int i = 0; i < 2; ++i)
      a[i] = *(const bf16x8*)(As + (wr + i * 16 + l15) * 32 + quad * 8);
#pragma unroll
    for (int j = 0; j < 8; ++j)
      b[j] = *(const bf16x8*)(Bs + (j * 16 + l15) * 32 + quad * 8);
#pragma unroll
    for (int i = 0; i < 2; ++i)
#pragma unroll
      for (int j = 0; j < 8; ++j)
        acc[i][j] = mfma16(a[i], b[j], acc[i][j]);
    __syncthreads();
  }

#pragma unroll
  for (int i = 0; i < 2; ++i)
#pragma unroll
    for (int j = 0; j < 4; ++j)
#pragma unroll
      for (int r = 0; r < 4; ++r) {
        const float g = acc[i][j][r], u = acc[i][j + 4][r];
        const float val = g * u / (1.0f + __expf(-g));
        const int row = nb * 128 + wr + i * 16 + quad * 4 + r;
        const int col = mb * 64 + j * 16 + l15;
        H[(size_t)row * DFF + col] = (bf16)val;
      }
}

// =====================================================================
// prep: RoPE on q/k, pack q, k_full, v_full (bf16)
// =====================================================================
__global__ __launch_bounds__(256) void prep_kernel(const float* __restrict__ qkv,
                                                   const float* __restrict__ kc,
                                                   const float* __restrict__ vc,
                                                   bf16* __restrict__ q,
                                                   bf16* __restrict__ kf,
                                                   bf16* __restrict__ vf) {
  int id = blockIdx.x * 256 + threadIdx.x;
  if (id < SEQ * HID) {                       // ---- q RoPE
    const int s = id >> 10, c = id & 1023;
    const int d = c & 63, j = d & 31;
    const float pos = (float)(HIST + s);
    const float inv = powf(10000.0f, -(float)(2 * j) / 64.0f);
    float sn, cs; sincosf(pos * inv, &sn, &cs);
    const float v0 = qkv[(size_t)s * NQKV + c];
    const float vp = (d < 32) ? qkv[(size_t)s * NQKV + c + 32]
                              : qkv[(size_t)s * NQKV + c - 32];
    const float r = (d < 32) ? (v0 * cs - vp * sn) : (v0 * cs + vp * sn);
    q[(size_t)s * HID + c] = (bf16)r;
    return;
  }
  id -= SEQ * HID;
  if (id < SEQ * 128) {                       // ---- k new RoPE
    const int s = id >> 7, c = id & 127;
    const int kvh = c >> 6, d = c & 63, j = d & 31;
    const float pos = (float)(HIST + s);
    const float inv = powf(10000.0f, -(float)(2 * j) / 64.0f);
    float sn, cs; sincosf(pos * inv, &sn, &cs);
    const float v0 = qkv[(size_t)s * NQKV + 1024 + c];
    const float vp = (d < 32) ? qkv[(size_t)s * NQKV + 1024 + c + 32]
                              : qkv[(size_t)s * NQKV + 1024 + c - 32];
    const float r = (d < 32) ? (v0 * cs - vp * sn) : (v0 * cs + vp * sn);
    kf[(size_t)kvh * KVSEQ * 64 + (size_t)(HIST + s) * 64 + d] = (bf16)r;
    return;
  }
  id -= SEQ * 128;
  if (id < SEQ * 128) {                       // ---- v new
    const int s = id >> 7, c = id & 127;
    const int kvh = c >> 6, d = c & 63;
    vf[(size_t)kvh * KVSEQ * 64 + (size_t)(HIST + s) * 64 + d] =
        (bf16)qkv[(size_t)s * NQKV + 1152 + c];
    return;
  }
  id -= SEQ * 128;
  if (id < 2 * 64 * HIST) {                   // ---- k cache (transpose)
    const int kvh = id >> 14, rem = id & 16383;
    const int d = rem >> 8, t = rem & 255;
    kf[(size_t)kvh * KVSEQ * 64 + (size_t)t * 64 + d] =
        (bf16)kc[(size_t)kvh * 64 * HIST + (size_t)d * HIST + t];
    return;
  }
  id -= 2 * 64 * HIST;
  {                                           // ---- v cache
    const int kvh = id >> 14, rem = id & 16383;
    const int t = rem >> 6, d = rem & 63;
    vf[(size_t)kvh * KVSEQ * 64 + (size_t)t * 64 + d] =
        (bf16)vc[(size_t)kvh * HIST * 64 + (size_t)t * 64 + d];
  }
}

// =====================================================================
// Flash attention (unchanged from R1, verified correct)
// =====================================================================
__global__ __launch_bounds__(256) void attn_kernel(const bf16* __restrict__ q,
                                                   const bf16* __restrict__ kf,
                                                   const bf16* __restrict__ vf,
                                                   const float* __restrict__ mask,
                                                   bf16* __restrict__ o) {
  const int qb = blockIdx.x;
  const int h  = blockIdx.y;
  const int kvh = h >> 3;
  const int tid = threadIdx.x;
  const int w = tid >> 6, lane = tid & 63, l15 = lane & 15, quad = lane >> 4;
  const float negm = -128.0f * mask[0];

  __shared__ bf16 Vt[64 * 40];
  __shared__ bf16 Pl[4][16 * 40];

  const int qr = qb * 64 + w * 16 + l15;
  const bf16* qbase = q + (size_t)qr * HID + h * 64;
  const bf16x8 aQ0 = *(const bf16x8*)(qbase + quad * 8);
  const bf16x8 aQ1 = *(const bf16x8*)(qbase + 32 + quad * 8);

  f32x4 Oacc[4] = {};
  float m_i[4], l_i[4];
#pragma unroll
  for (int r = 0; r < 4; ++r) { m_i[r] = -INFINITY; l_i[r] = 0.f; }

  const int qrow0 = qb * 64 + w * 16 + quad * 4;
  const int ntiles = qb * 2 + 2;
  const bf16* kbase = kf + (size_t)kvh * KVSEQ * 64;
  const bf16* vbase = vf + (size_t)kvh * KVSEQ * 64;
  bf16* pw = &Pl[w][0];

  for (int t = 0; t < ntiles; ++t) {
    __syncthreads();
    {
      const int vp = tid >> 3, d0 = (tid & 7) * 8;
      bf16x8 vv = *(const bf16x8*)(vbase + (size_t)(t * 32 + vp) * 64 + d0);
#pragma unroll
      for (int jj = 0; jj < 8; ++jj) Vt[(d0 + jj) * 40 + vp] = vv[jj];
    }
    __syncthreads();

    f32x4 S[2];
#pragma unroll
    for (int u = 0; u < 2; ++u) {
      const bf16* kp = kbase + (size_t)(t * 32 + u * 16 + l15) * 64;
      bf16x8 b0 = *(const bf16x8*)(kp + quad * 8);
      bf16x8 b1 = *(const bf16x8*)(kp + 32 + quad * 8);
      f32x4 z = {0.f, 0.f, 0.f, 0.f};
      S[u] = mfma16(aQ0, b0, z);
      S[u] = mfma16(aQ1, b1, S[u]);
    }
    const int kj = t * 32 + l15;
#pragma unroll
    for (int u = 0; u < 2; ++u)
#pragma unroll
      for (int r = 0; r < 4; ++r)
        S[u][r] += ((kj + u * 16) <= (qrow0 + r)) ? 0.f : negm;

    float p0[4], p1[4];
#pragma unroll
    for (int r = 0; r < 4; ++r) {
      float vm = fmaxf(S[0][r], S[1][r]);
#pragma unroll
      for (int off = 1; off < 16; off <<= 1) vm = fmaxf(vm, __shfl_xor(vm, off));
      const float mnew = fmaxf(m_i[r], vm);
      const float alpha = __expf(m_i[r] - mnew);
      p0[r] = __expf(S[0][r] - mnew);
      p1[r] = __expf(S[1][r] - mnew);
      float rs = p0[r] + p1[r];
#pragma unroll
      for (int off = 1; off < 16; off <<= 1) rs += __shfl_xor(rs, off);
      l_i[r] = l_i[r] * alpha + rs;
      m_i[r] = mnew;
#pragma unroll
      for (int j = 0; j < 4; ++j) Oacc[j][r] *= alpha;
    }

#pragma unroll
    for (int r = 0; r < 4; ++r) {
      pw[(quad * 4 + r) * 40 + l15]      = (bf16)p0[r];
      pw[(quad * 4 + r) * 40 + 16 + l15] = (bf16)p1[r];
    }
    const bf16x8 aP = *(const bf16x8*)(pw + l15 * 40 + quad * 8);
#pragma unroll
    for (int j = 0; j < 4; ++j) {
      bf16x8 bV = *(const bf16x8*)(&Vt[(j * 16 + l15) * 40 + quad * 8]);
      Oacc[j] = mfma16(aP, bV, Oacc[j]);
    }
  }

#pragma unroll
  for (int j = 0; j < 4; ++j)
#pragma unroll
    for (int r = 0; r < 4; ++r) {
      const int row = qb * 64 + w * 16 + quad * 4 + r;
      o[(size_t)row * HID + h * 64 + j * 16 + l15] = (bf16)(Oacc[j][r] / l_i[r]);
    }
}

// =====================================================================
// launch
// =====================================================================
extern "C" void kernel_launch(void* const* d_in, const int* in_sizes, int n_in,
                              void* d_out, int out_size, void* d_ws, size_t ws_size,
                              hipStream_t stream) {
  const float* hidden  = (const float*)d_in[0];
  const float* feat    = (const float*)d_in[1];
  const float* qkv_w   = (const float*)d_in[2];
  const float* o_w     = (const float*)d_in[3];
  const float* gu_w    = (const float*)d_in[4];
  const float* down_w  = (const float*)d_in[5];
  const float* norm_w  = (const float*)d_in[6];
  const float* fsq_w   = (const float*)d_in[7];
  const float* k_cache = (const float*)d_in[8];
  const float* v_cache = (const float*)d_in[9];
  const float* mask    = (const float*)d_in[10];
  float* x = (float*)d_out;   // residual stream lives in d_out

  char* p = (char*)d_ws;
  bf16*  xn   = (bf16*)p;  p += (size_t)SEQ * HID * 2;        // 2 MB
  float* qkvb = (float*)p; p += (size_t)SEQ * NQKV * 4;       // 5.24 MB
  bf16*  qb   = (bf16*)p;  p += (size_t)SEQ * HID * 2;        // 2 MB
  bf16*  kfb  = (bf16*)p;  p += (size_t)2 * KVSEQ * 64 * 2;   // 0.33 MB
  bf16*  vfb  = (bf16*)p;  p += (size_t)2 * KVSEQ * 64 * 2;   // 0.33 MB
  bf16*  ob   = (bf16*)p;  p += (size_t)SEQ * HID * 2;        // 2 MB
  bf16*  hb   = (bf16*)p;  p += (size_t)SEQ * DFF * 2;        // 8 MB
  bf16*  wq   = (bf16*)p;  p += (size_t)NQKV * HID * 2;       // 2.62 MB
  bf16*  wo   = (bf16*)p;  p += (size_t)HID * HID * 2;        // 2.10 MB
  bf16*  wgu  = (bf16*)p;  p += (size_t)2 * DFF * HID * 2;    // 16.78 MB
  bf16*  wdn  = (bf16*)p;  p += (size_t)HID * DFF * 2;        // 8.39 MB
  bf16*  wfsq = (bf16*)p;  p += (size_t)HID * HID * 2;        // 2.10 MB

  hipMemcpyAsync(x, hidden, (size_t)SEQ * HID * 4, hipMemcpyDeviceToDevice, stream);

  for (int l = 0; l < 12; ++l) {
    const bool mid = (l == 6);
    convert_kernel<<<mid ? 15616 : 14592, 256, 0, stream>>>(
        (const float4*)(qkv_w + (size_t)l * NQKV * HID),
        (const float4*)(o_w + (size_t)l * HID * HID),
        (const float4*)(gu_w + (size_t)l * 2 * DFF * HID),
        (const float4*)(down_w + (size_t)l * HID * DFF),
        mid ? (const float4*)fsq_w : nullptr,
        (bf16x4*)wq, (bf16x4*)wo, (bf16x4*)wgu, (bf16x4*)wdn, (bf16x4*)wfsq);

    if (mid) {
      finalnorm_kernel<<<SEQ, 256, 0, stream>>>(x, norm_w, xn);
      hipMemcpyAsync(x + (size_t)CTL * HID, feat, (size_t)(SEQ - CTL) * HID * 4,
                     hipMemcpyDeviceToDevice, stream);
      // x[CTL:] = feat + hn[CTL:] @ fsq^T   (split-4 atomic)
      gemm128<<<dim3(HID / 128, (SEQ - CTL) / 128, 4), 256, 0, stream>>>(
          xn + (size_t)CTL * HID, wfsq, x + (size_t)CTL * HID, HID, HID, 8);
    }

    l2norm_kernel<<<SEQ, 256, 0, stream>>>(x, xn);
    hipMemsetAsync(qkvb, 0, (size_t)SEQ * NQKV * 4, stream);
    gemm128<<<dim3(NQKV / 128, SEQ / 128, 2), 256, 0, stream>>>(
        xn, wq, qkvb, NQKV, HID, 16);
    prep_kernel<<<5376, 256, 0, stream>>>(
        qkvb, k_cache + (size_t)l * 2 * 64 * HIST,
        v_cache + (size_t)l * 2 * HIST * 64, qb, kfb, vfb);
    attn_kernel<<<dim3(SEQ / 64, NHEAD), 256, 0, stream>>>(qb, kfb, vfb, mask, ob);
    gemm128<<<dim3(HID / 128, SEQ / 128, 4), 256, 0, stream>>>(
        ob, wo, x, HID, HID, 8);
    l2norm_kernel<<<SEQ, 256, 0, stream>>>(x, xn);
    gemm_gu<<<dim3(DFF / 64, SEQ / 128), 256, 0, stream>>>(xn, wgu, hb, HID);
    gemm128<<<dim3(HID / 128, SEQ / 128, 4), 256, 0, stream>>>(
        hb, wdn, x, HID, DFF, 32);
  }
}